// Round 1
// baseline (514.566 us; speedup 1.0000x reference)
//
#include <hip/hip_runtime.h>
#include <math.h>

#define N_TOTAL   262144      // 256 graphs * 1024 nodes
#define E_TOTAL   8388608     // N_TOTAL * 32
#define EPG       32768       // edges per graph
#define D_FEAT    128
#define NUM_G     256
#define NPG       1024
#define KSEL      820         // ceil(0.8 * 1024)
#define BK        (NUM_G * KSEL)   // 209920

#define FP_SCALE     4503599627370496.0   // 2^52: fixed-point scale for deterministic agg
#define FP_INV_SCALE (1.0 / FP_SCALE)

typedef float  f32x4 __attribute__((ext_vector_type(4)));
typedef int    i32x4 __attribute__((ext_vector_type(4)));

// ---------------------------------------------------------------------------
// K1: xw[i] = dot(x[i,:], W[:,0]) in double. One wave (64 lanes) per node,
// each lane loads a float2 (coalesced 8B/lane).
// ---------------------------------------------------------------------------
__global__ void xw_kernel(const float* __restrict__ x, const float* __restrict__ W,
                          double* __restrict__ xw) {
    int gtid = blockIdx.x * blockDim.x + threadIdx.x;
    int node = gtid >> 6;
    int lane = threadIdx.x & 63;
    if (node >= N_TOTAL) return;
    float2 xv = ((const float2*)x)[(size_t)node * 64 + lane];
    float2 wv = ((const float2*)W)[lane];
    double s = (double)xv.x * (double)wv.x + (double)xv.y * (double)wv.y;
    #pragma unroll
    for (int off = 32; off > 0; off >>= 1) s += __shfl_down(s, off, 64);
    if (lane == 0) xw[node] = s;
}

// ---------------------------------------------------------------------------
// K2 (fused, one block of 1024 threads per graph):
//   deg (LDS int atomics) -> dinv -> m = dinv*xw (per node, once) ->
//   agg[d] += m[s] (LDS int64 fixed-point atomics, deterministic;
//   dinv[d] factored OUT of the sum) -> score = dinv*(agg+m)+b ->
//   rank-count top-k -> local node map -> edge outputs (nontemporal).
//   Factorized agg: 1 random LDS read + 1 const FP64 mul per edge
//   (was 3 reads + 3 muls); self-loop divide folded into dinv^2.
// ---------------------------------------------------------------------------
__global__ __launch_bounds__(1024, 1)
void graph_kernel(const int* __restrict__ ei, const double* __restrict__ xw,
                  const float* __restrict__ bptr,
                  int* __restrict__ permInt, float* __restrict__ scaleF,
                  float* __restrict__ out_batch, float* __restrict__ out_perm,
                  float* __restrict__ out_ei0, float* __restrict__ out_ei1,
                  float* __restrict__ out_mask) {
    __shared__ double    mS[NPG];      // 8 KB  (xw on load, then m = dinv*xw)
    __shared__ int       degS[NPG];    // 4 KB
    __shared__ double    dinvS[NPG];   // 8 KB
    __shared__ long long aggS[NPG];    // 8 KB
    __shared__ float     scoreS[NPG];  // 4 KB
    __shared__ int       lmap[NPG];    // 4 KB   -> 36 KB total

    const int g    = blockIdx.x;
    const int tid  = threadIdx.x;
    const int base = g * NPG;
    const int4* src4 = (const int4*)(ei + (size_t)g * EPG);
    const int4* dst4 = (const int4*)(ei + E_TOTAL + (size_t)g * EPG);

    mS[tid]   = xw[base + tid];   // holds xw for now
    degS[tid] = 0;
    aggS[tid] = 0;
    __syncthreads();

    // --- degree (in-edges) ---
    #pragma unroll
    for (int k = 0; k < 8; k++) {
        int4 d = dst4[tid + k * 1024];
        atomicAdd(&degS[d.x - base], 1);
        atomicAdd(&degS[d.y - base], 1);
        atomicAdd(&degS[d.z - base], 1);
        atomicAdd(&degS[d.w - base], 1);
    }
    __syncthreads();
    {
        double dinv = 1.0 / sqrt((double)(degS[tid] + 1));
        dinvS[tid] = dinv;
        mS[tid]    = dinv * mS[tid];   // m[i] = dinv[i]*xw[i] (own slot: race-free)
    }
    __syncthreads();

    // --- aggregate: agg[d] += m[s], int64 fixed point (dinv[d] factored out) ---
    #pragma unroll
    for (int k = 0; k < 8; k++) {
        int4 s = src4[tid + k * 1024];
        int4 d = dst4[tid + k * 1024];
        double tx = mS[s.x - base];
        double ty = mS[s.y - base];
        double tz = mS[s.z - base];
        double tw = mS[s.w - base];
        atomicAdd((unsigned long long*)&aggS[d.x - base], (unsigned long long)(long long)(tx * FP_SCALE));
        atomicAdd((unsigned long long*)&aggS[d.y - base], (unsigned long long)(long long)(ty * FP_SCALE));
        atomicAdd((unsigned long long*)&aggS[d.z - base], (unsigned long long)(long long)(tz * FP_SCALE));
        atomicAdd((unsigned long long*)&aggS[d.w - base], (unsigned long long)(long long)(tw * FP_SCALE));
    }
    __syncthreads();

    // --- score: dinv*(sum_in + m_self) + b   (self-loop: xw/(deg+1) = dinv*m) ---
    {
        double sum = (double)aggS[tid] * FP_INV_SCALE + mS[tid];
        double sc  = dinvS[tid] * sum + (double)bptr[0];
        scoreS[tid] = (float)sc;
    }
    __syncthreads();

    // --- exact top-k by rank counting (float compares, float4 broadcast) ---
    // rank_i = #{ j : s_j > s_i  or (s_j == s_i and j < i) }  == jax.lax.top_k order
    {
        float si = scoreS[tid];
        int rank = 0;
        const float4* s4 = (const float4*)scoreS;
        for (int j = 0; j < NPG / 4; j++) {
            float4 c = s4[j];
            int j0 = j * 4;
            rank += (c.x > si) || (c.x == si && (j0 + 0) < tid);
            rank += (c.y > si) || (c.y == si && (j0 + 1) < tid);
            rank += (c.z > si) || (c.z == si && (j0 + 2) < tid);
            rank += (c.w > si) || (c.w == si && (j0 + 3) < tid);
        }
        int pos = -1;
        if (rank < KSEL) {
            pos = g * KSEL + rank;
            int node = base + tid;
            permInt[pos]   = node;
            scaleF[pos]    = tanhf(si);
            __builtin_nontemporal_store((float)g,    out_batch + pos);
            __builtin_nontemporal_store((float)node, out_perm  + pos);
        }
        lmap[tid] = pos;  // -1 if dropped; else global retained position
    }
    __syncthreads();

    // --- edge outputs: mask + reindexed endpoints (LDS-resident map) ---
    // Last use of ei in this kernel: nontemporal loads; outputs are
    // write-only streams: nontemporal stores (protect x/ei in LLC).
    #pragma unroll
    for (int k = 0; k < 8; k++) {
        int idx = tid + k * 1024;               // int4 group within graph
        i32x4 s = __builtin_nontemporal_load((const i32x4*)src4 + idx);
        i32x4 d = __builtin_nontemporal_load((const i32x4*)dst4 + idx);
        f32x4 e0, e1, m;
        int ms, md; bool kp;
        ms = lmap[s.x - base]; md = lmap[d.x - base]; kp = (ms >= 0) && (md >= 0);
        e0.x = kp ? (float)ms : -1.0f; e1.x = kp ? (float)md : -1.0f; m.x = kp ? 1.0f : 0.0f;
        ms = lmap[s.y - base]; md = lmap[d.y - base]; kp = (ms >= 0) && (md >= 0);
        e0.y = kp ? (float)ms : -1.0f; e1.y = kp ? (float)md : -1.0f; m.y = kp ? 1.0f : 0.0f;
        ms = lmap[s.z - base]; md = lmap[d.z - base]; kp = (ms >= 0) && (md >= 0);
        e0.z = kp ? (float)ms : -1.0f; e1.z = kp ? (float)md : -1.0f; m.z = kp ? 1.0f : 0.0f;
        ms = lmap[s.w - base]; md = lmap[d.w - base]; kp = (ms >= 0) && (md >= 0);
        e0.w = kp ? (float)ms : -1.0f; e1.w = kp ? (float)md : -1.0f; m.w = kp ? 1.0f : 0.0f;
        size_t o = (size_t)g * (EPG / 4) + idx;
        __builtin_nontemporal_store(e0, (f32x4*)out_ei0  + o);
        __builtin_nontemporal_store(e1, (f32x4*)out_ei1  + o);
        __builtin_nontemporal_store(m,  (f32x4*)out_mask + o);
    }
}

// ---------------------------------------------------------------------------
// K3: gather retained rows; x_ae = x[perm], x_out = x_ae * tanh(score[perm]).
// 32 lanes per row (float4/lane), tanh precomputed per row. Streaming
// outputs stored nontemporally.
// ---------------------------------------------------------------------------
__global__ void gather_kernel(const float* __restrict__ x, const int* __restrict__ permInt,
                              const float* __restrict__ scaleF,
                              float* __restrict__ out_xout, float* __restrict__ out_xae) {
    int gtid = blockIdx.x * blockDim.x + threadIdx.x;
    int row  = gtid >> 5;
    int lane = gtid & 31;
    if (row >= BK) return;
    int node = permInt[row];
    float t = scaleF[row];
    f32x4 v = *((const f32x4*)x + (size_t)node * 32 + lane);
    f32x4 o = v * t;
    __builtin_nontemporal_store(v, (f32x4*)out_xae  + (size_t)row * 32 + lane);
    __builtin_nontemporal_store(o, (f32x4*)out_xout + (size_t)row * 32 + lane);
}

extern "C" void kernel_launch(void* const* d_in, const int* in_sizes, int n_in,
                              void* d_out, int out_size, void* d_ws, size_t ws_size,
                              hipStream_t stream) {
    const float* x  = (const float*)d_in[0];
    const int*   ei = (const int*)d_in[1];     // [2, E]: src then dst
    // d_in[2] = batch (unused; graphs are block-contiguous, recomputed)
    const float* W  = (const float*)d_in[3];
    const float* b  = (const float*)d_in[4];

    // workspace layout
    double* xw      = (double*)d_ws;           // N doubles
    int*    permInt = (int*)(xw + N_TOTAL);    // BK ints
    float*  scaleF  = (float*)(permInt + BK);  // BK floats

    // output layout (all float32, concatenated in reference return order)
    float* out       = (float*)d_out;
    float* out_xout  = out;                          // BK*128
    float* out_ei0   = out + (size_t)BK * D_FEAT;    // E
    float* out_ei1   = out_ei0 + E_TOTAL;            // E
    float* out_mask  = out_ei1 + E_TOTAL;            // E
    float* out_batch = out_mask + E_TOTAL;           // BK
    float* out_perm  = out_batch + BK;               // BK
    float* out_xae   = out_perm + BK;                // BK*128

    xw_kernel<<<(N_TOTAL * 64) / 256, 256, 0, stream>>>(x, W, xw);
    graph_kernel<<<NUM_G, 1024, 0, stream>>>(ei, xw, b, permInt, scaleF,
                                             out_batch, out_perm,
                                             out_ei0, out_ei1, out_mask);
    gather_kernel<<<(BK * 32 + 255) / 256, 256, 0, stream>>>(x, permInt, scaleF,
                                                             out_xout, out_xae);
}

// Round 2
// 466.441 us; speedup vs baseline: 1.1032x; 1.1032x over previous
//
#include <hip/hip_runtime.h>
#include <math.h>

#define N_TOTAL   262144      // 256 graphs * 1024 nodes
#define E_TOTAL   8388608     // N_TOTAL * 32
#define EPG       32768       // edges per graph
#define D_FEAT    128
#define NUM_G     256
#define NPG       1024
#define KSEL      820         // ceil(0.8 * 1024)
#define BK        (NUM_G * KSEL)   // 209920

#define FP_SCALE     4503599627370496.0   // 2^52 fixed-point scale (deterministic agg)
#define FP_INV_SCALE (1.0 / FP_SCALE)

typedef float  f32x4 __attribute__((ext_vector_type(4)));
typedef int    i32x4 __attribute__((ext_vector_type(4)));

// ---------------------------------------------------------------------------
// Single fused kernel: one block of 1024 threads per graph.
// Phases: xw (in-block f64 dot) -> deg -> dinv/m -> agg (int64 fixed-point,
// deterministic) -> score -> histogram top-k (exact rank, 1024 bins) ->
// gather (x_ae/x_out) -> edge outputs.
// dst edge list persists in 32 VGPRs (loaded once, NT); src NT-loaded twice.
// All streaming outputs nontemporal to keep x LLC-resident for the gather.
// ---------------------------------------------------------------------------
__global__ __launch_bounds__(1024, 1)
void sagpool_fused(const float* __restrict__ x, const int* __restrict__ ei,
                   const float* __restrict__ Wp, const float* __restrict__ bptr,
                   float* __restrict__ out_xout, float* __restrict__ out_xae,
                   float* __restrict__ out_ei0, float* __restrict__ out_ei1,
                   float* __restrict__ out_mask,
                   float* __restrict__ out_batch, float* __restrict__ out_perm)
{
    __shared__ double    mS[NPG];      // xw -> m; later: mlist (int[1024]) + cursor (int[1024])
    __shared__ int       degS[NPG];    // deg; later: rankNode
    __shared__ double    dinvS[NPG];   // dinv; later: hist (uint[1024]) + scanA (uint[1024])
    __shared__ long long aggS[NPG];    // agg; later: keyS (uint[1024]) + scanB/scaleR
    __shared__ float     scoreS[NPG];
    __shared__ int       lmap[NPG];    // 36 KB total

    const int g    = blockIdx.x;
    const int tid  = threadIdx.x;
    const int base = g * NPG;
    const i32x4* src4 = (const i32x4*)(ei + (size_t)g * EPG);
    const i32x4* dst4 = (const i32x4*)(ei + E_TOTAL + (size_t)g * EPG);
    const float  bb   = bptr[0];

    degS[tid] = 0;
    aggS[tid] = 0;

    // --- phase 0: xw (f64 dot) for own rows: 16 lanes/row, float8 per lane ---
    {
        const int lane16 = tid & 15;
        const int rgrp   = tid >> 4;          // 0..63
        f32x4 w0 = ((const f32x4*)Wp)[lane16 * 2];
        f32x4 w1 = ((const f32x4*)Wp)[lane16 * 2 + 1];
        double wd0 = w0.x, wd1 = w0.y, wd2 = w0.z, wd3 = w0.w;
        double wd4 = w1.x, wd5 = w1.y, wd6 = w1.z, wd7 = w1.w;
        #pragma unroll
        for (int p = 0; p < 16; p++) {
            int row = p * 64 + rgrp;
            const f32x4* xr = (const f32x4*)(x + (size_t)(base + row) * D_FEAT) + lane16 * 2;
            f32x4 a = xr[0];
            f32x4 c = xr[1];
            double s = (double)a.x * wd0 + (double)a.y * wd1 +
                       (double)a.z * wd2 + (double)a.w * wd3 +
                       (double)c.x * wd4 + (double)c.y * wd5 +
                       (double)c.z * wd6 + (double)c.w * wd7;
            s += __shfl_xor(s, 8, 16);
            s += __shfl_xor(s, 4, 16);
            s += __shfl_xor(s, 2, 16);
            s += __shfl_xor(s, 1, 16);
            if (lane16 == 0) mS[row] = s;
        }
    }

    // --- load dst edge list once (persists in 32 VGPRs), nontemporal ---
    i32x4 dreg[8];
    #pragma unroll
    for (int k = 0; k < 8; k++)
        dreg[k] = __builtin_nontemporal_load(dst4 + tid + k * 1024);

    __syncthreads();   // mS (xw), degS=0, aggS=0 all visible

    // --- degree ---
    #pragma unroll
    for (int k = 0; k < 8; k++) {
        atomicAdd(&degS[dreg[k].x - base], 1);
        atomicAdd(&degS[dreg[k].y - base], 1);
        atomicAdd(&degS[dreg[k].z - base], 1);
        atomicAdd(&degS[dreg[k].w - base], 1);
    }
    __syncthreads();
    {
        double dinv = 1.0 / sqrt((double)(degS[tid] + 1));
        dinvS[tid] = dinv;
        mS[tid]    = dinv * mS[tid];   // m[i] = dinv[i]*xw[i]
    }
    __syncthreads();

    // --- aggregate: agg[d] += m[s] (int64 fixed point; dinv[d] factored out) ---
    #pragma unroll
    for (int k = 0; k < 8; k++) {
        i32x4 s = __builtin_nontemporal_load(src4 + tid + k * 1024);
        double tx = mS[s.x - base];
        double ty = mS[s.y - base];
        double tz = mS[s.z - base];
        double tw = mS[s.w - base];
        atomicAdd((unsigned long long*)&aggS[dreg[k].x - base], (unsigned long long)(long long)(tx * FP_SCALE));
        atomicAdd((unsigned long long*)&aggS[dreg[k].y - base], (unsigned long long)(long long)(ty * FP_SCALE));
        atomicAdd((unsigned long long*)&aggS[dreg[k].z - base], (unsigned long long)(long long)(tz * FP_SCALE));
        atomicAdd((unsigned long long*)&aggS[dreg[k].w - base], (unsigned long long)(long long)(tw * FP_SCALE));
    }
    __syncthreads();

    // --- score ---
    float si;
    {
        double sum = (double)aggS[tid] * FP_INV_SCALE + mS[tid];
        si = (float)(dinvS[tid] * sum + (double)bb);
        scoreS[tid] = si;
    }
    __syncthreads();   // all reads of aggS/mS/dinvS complete -> safe to reuse

    // --- exact top-k via 1024-bin histogram on sortable keys ---
    uint32_t* keyS     = (uint32_t*)aggS;         // [1024]
    uint32_t* scanB    = keyS + NPG;              // [1024]
    float*    scaleR   = (float*)scanB;           // reused after scan completes
    uint32_t* hist     = (uint32_t*)dinvS;        // [1024]
    uint32_t* scanA    = hist + NPG;              // [1024]
    int*      mlist    = (int*)mS;                // [1024]
    int*      cursorS  = mlist + NPG;             // [1024]
    int*      rankNode = degS;                    // [1024]

    uint32_t sb = __float_as_uint(si);
    if (sb == 0x80000000u) sb = 0u;               // canonicalize -0 -> +0
    const uint32_t key = (sb & 0x80000000u) ? ~sb : (sb | 0x80000000u); // ascending order key
    keyS[tid]    = key;
    hist[tid]    = 0u;
    cursorS[tid] = 0;
    __syncthreads();

    const int bin = (int)(key >> 22);             // 1024 bins (sign+exp+2 mantissa bits)
    atomicAdd(&hist[bin], 1u);
    __syncthreads();

    // inclusive suffix scan of hist (ping-pong Hillis-Steele; 10 steps -> result in scanA)
    {
        uint32_t* A = scanA;
        uint32_t* B = scanB;
        A[tid] = hist[tid];
        __syncthreads();
        #pragma unroll
        for (int off = 1; off < NPG; off <<= 1) {
            uint32_t v = A[tid] + ((tid + off < NPG) ? A[tid + off] : 0u);
            B[tid] = v;
            __syncthreads();
            uint32_t* t = A; A = B; B = t;
        }
    }

    const int myStart = (int)(scanA[bin] - hist[bin]);   // # nodes in strictly-higher bins
    {
        int slot = myStart + atomicAdd(&cursorS[bin], 1);
        mlist[slot] = tid;
    }
    __syncthreads();

    int rank = myStart;
    {
        const int h = (int)hist[bin];
        for (int m = 0; m < h; m++) {
            int j = mlist[myStart + m];
            uint32_t kj = keyS[j];
            rank += (kj > key) || (kj == key && j < tid);
        }
    }
    int pos = -1;
    if (rank < KSEL) {
        pos = g * KSEL + rank;
        rankNode[rank] = tid;
        scaleR[rank]   = tanhf(si);
        __builtin_nontemporal_store((float)g,            out_batch + pos);
        __builtin_nontemporal_store((float)(base + tid), out_perm  + pos);
    }
    lmap[tid] = pos;
    __syncthreads();

    // --- gather: x_ae = x[perm], x_out = x_ae * tanh(score) (32 lanes/row) ---
    {
        const int lane32 = tid & 31;
        const int rowgrp = tid >> 5;              // 0..31
        #pragma unroll
        for (int p = 0; p < 26; p++) {
            int r = p * 32 + rowgrp;
            if (r < KSEL) {
                int node = rankNode[r];
                float t  = scaleR[r];
                f32x4 v = *((const f32x4*)x + (size_t)(base + node) * 32 + lane32);
                f32x4 o = v * t;
                size_t orow = (size_t)(g * KSEL + r) * 32 + lane32;
                __builtin_nontemporal_store(v, (f32x4*)out_xae  + orow);
                __builtin_nontemporal_store(o, (f32x4*)out_xout + orow);
            }
        }
    }

    // --- edge outputs: mask + reindexed endpoints (lmap in LDS) ---
    #pragma unroll
    for (int k = 0; k < 8; k++) {
        int idx = tid + k * 1024;
        i32x4 s = __builtin_nontemporal_load(src4 + idx);
        i32x4 d = dreg[k];
        f32x4 e0, e1, m;
        int ms, md; bool kp;
        ms = lmap[s.x - base]; md = lmap[d.x - base]; kp = (ms >= 0) && (md >= 0);
        e0.x = kp ? (float)ms : -1.0f; e1.x = kp ? (float)md : -1.0f; m.x = kp ? 1.0f : 0.0f;
        ms = lmap[s.y - base]; md = lmap[d.y - base]; kp = (ms >= 0) && (md >= 0);
        e0.y = kp ? (float)ms : -1.0f; e1.y = kp ? (float)md : -1.0f; m.y = kp ? 1.0f : 0.0f;
        ms = lmap[s.z - base]; md = lmap[d.z - base]; kp = (ms >= 0) && (md >= 0);
        e0.z = kp ? (float)ms : -1.0f; e1.z = kp ? (float)md : -1.0f; m.z = kp ? 1.0f : 0.0f;
        ms = lmap[s.w - base]; md = lmap[d.w - base]; kp = (ms >= 0) && (md >= 0);
        e0.w = kp ? (float)ms : -1.0f; e1.w = kp ? (float)md : -1.0f; m.w = kp ? 1.0f : 0.0f;
        size_t o = (size_t)g * (EPG / 4) + idx;
        __builtin_nontemporal_store(e0, (f32x4*)out_ei0  + o);
        __builtin_nontemporal_store(e1, (f32x4*)out_ei1  + o);
        __builtin_nontemporal_store(m,  (f32x4*)out_mask + o);
    }
}

extern "C" void kernel_launch(void* const* d_in, const int* in_sizes, int n_in,
                              void* d_out, int out_size, void* d_ws, size_t ws_size,
                              hipStream_t stream) {
    const float* x  = (const float*)d_in[0];
    const int*   ei = (const int*)d_in[1];     // [2, E]: src then dst
    // d_in[2] = batch (unused; graphs are block-contiguous, recomputed)
    const float* W  = (const float*)d_in[3];
    const float* b  = (const float*)d_in[4];

    // output layout (all float32, concatenated in reference return order)
    float* out       = (float*)d_out;
    float* out_xout  = out;                          // BK*128
    float* out_ei0   = out + (size_t)BK * D_FEAT;    // E
    float* out_ei1   = out_ei0 + E_TOTAL;            // E
    float* out_mask  = out_ei1 + E_TOTAL;            // E
    float* out_batch = out_mask + E_TOTAL;           // BK
    float* out_perm  = out_batch + BK;               // BK
    float* out_xae   = out_perm + BK;                // BK*128

    sagpool_fused<<<NUM_G, 1024, 0, stream>>>(x, ei, W, b,
                                              out_xout, out_xae,
                                              out_ei0, out_ei1, out_mask,
                                              out_batch, out_perm);
}

// Round 3
// 463.805 us; speedup vs baseline: 1.1094x; 1.0057x over previous
//
#include <hip/hip_runtime.h>
#include <math.h>

#define N_TOTAL   262144      // 256 graphs * 1024 nodes
#define E_TOTAL   8388608     // N_TOTAL * 32
#define EPG       32768       // edges per graph
#define D_FEAT    128
#define NUM_G     256
#define NPG       1024
#define KSEL      820         // ceil(0.8 * 1024)
#define BK        (NUM_G * KSEL)   // 209920

#define FP_SCALE     4503599627370496.0   // 2^52 fixed-point scale (deterministic agg)
#define FP_INV_SCALE (1.0 / FP_SCALE)

typedef float  f32x4 __attribute__((ext_vector_type(4)));
typedef int    i32x4 __attribute__((ext_vector_type(4)));

// ---------------------------------------------------------------------------
// Single fused kernel: one block of 1024 threads per graph.
// Phases: xw (in-block f64 dot) -> deg -> dinv/m -> agg (int64 fixed-point,
// deterministic) -> score -> histogram top-k (exact rank; single-wave suffix
// scan) -> gather (x_ae/x_out) -> edge outputs.
// dst edge list persists in 32 VGPRs (loaded once, NT). src loaded regular
// in agg (populates L2/LLC for edge-phase re-read), NT on last use.
// Streaming outputs nontemporal to keep x LLC-resident for the gather.
// ---------------------------------------------------------------------------
__global__ __launch_bounds__(1024, 1)
void sagpool_fused(const float* __restrict__ x, const int* __restrict__ ei,
                   const float* __restrict__ Wp, const float* __restrict__ bptr,
                   float* __restrict__ out_xout, float* __restrict__ out_xae,
                   float* __restrict__ out_ei0, float* __restrict__ out_ei1,
                   float* __restrict__ out_mask,
                   float* __restrict__ out_batch, float* __restrict__ out_perm)
{
    __shared__ double    mS[NPG];      // xw -> m; later: mlist (int[1024]) + cursor (int[1024])
    __shared__ int       degS[NPG];    // deg; later: rankNode
    __shared__ double    dinvS[NPG];   // dinv; later: hist (uint[1024]) + scanA (uint[1024])
    __shared__ long long aggS[NPG];    // agg; later: keyS (uint[1024]) + scaleR area
    __shared__ float     scoreS[NPG];
    __shared__ int       lmap[NPG];    // 36 KB total

    const int g    = blockIdx.x;
    const int tid  = threadIdx.x;
    const int base = g * NPG;
    const i32x4* src4 = (const i32x4*)(ei + (size_t)g * EPG);
    const i32x4* dst4 = (const i32x4*)(ei + E_TOTAL + (size_t)g * EPG);
    const float  bb   = bptr[0];

    degS[tid] = 0;
    aggS[tid] = 0;

    // --- phase 0: xw (f64 dot) for own rows: 16 lanes/row, float8 per lane ---
    {
        const int lane16 = tid & 15;
        const int rgrp   = tid >> 4;          // 0..63
        f32x4 w0 = ((const f32x4*)Wp)[lane16 * 2];
        f32x4 w1 = ((const f32x4*)Wp)[lane16 * 2 + 1];
        double wd0 = w0.x, wd1 = w0.y, wd2 = w0.z, wd3 = w0.w;
        double wd4 = w1.x, wd5 = w1.y, wd6 = w1.z, wd7 = w1.w;
        #pragma unroll
        for (int p = 0; p < 16; p++) {
            int row = p * 64 + rgrp;
            const f32x4* xr = (const f32x4*)(x + (size_t)(base + row) * D_FEAT) + lane16 * 2;
            f32x4 a = xr[0];
            f32x4 c = xr[1];
            double s = (double)a.x * wd0 + (double)a.y * wd1 +
                       (double)a.z * wd2 + (double)a.w * wd3 +
                       (double)c.x * wd4 + (double)c.y * wd5 +
                       (double)c.z * wd6 + (double)c.w * wd7;
            s += __shfl_xor(s, 8, 16);
            s += __shfl_xor(s, 4, 16);
            s += __shfl_xor(s, 2, 16);
            s += __shfl_xor(s, 1, 16);
            if (lane16 == 0) mS[row] = s;
        }
    }

    // --- load dst edge list once (persists in 32 VGPRs), nontemporal ---
    i32x4 dreg[8];
    #pragma unroll
    for (int k = 0; k < 8; k++)
        dreg[k] = __builtin_nontemporal_load(dst4 + tid + k * 1024);

    __syncthreads();   // mS (xw), degS=0, aggS=0 all visible

    // --- degree ---
    #pragma unroll
    for (int k = 0; k < 8; k++) {
        atomicAdd(&degS[dreg[k].x - base], 1);
        atomicAdd(&degS[dreg[k].y - base], 1);
        atomicAdd(&degS[dreg[k].z - base], 1);
        atomicAdd(&degS[dreg[k].w - base], 1);
    }
    __syncthreads();
    {
        double dinv = 1.0 / sqrt((double)(degS[tid] + 1));
        dinvS[tid] = dinv;
        mS[tid]    = dinv * mS[tid];   // m[i] = dinv[i]*xw[i]
    }
    __syncthreads();

    // --- aggregate: agg[d] += m[s] (int64 fixed point; dinv[d] factored out) ---
    // src loads REGULAR here: they populate L2/LLC for the edge-phase re-read.
    #pragma unroll
    for (int k = 0; k < 8; k++) {
        i32x4 s = src4[tid + k * 1024];
        double tx = mS[s.x - base];
        double ty = mS[s.y - base];
        double tz = mS[s.z - base];
        double tw = mS[s.w - base];
        atomicAdd((unsigned long long*)&aggS[dreg[k].x - base], (unsigned long long)(long long)(tx * FP_SCALE));
        atomicAdd((unsigned long long*)&aggS[dreg[k].y - base], (unsigned long long)(long long)(ty * FP_SCALE));
        atomicAdd((unsigned long long*)&aggS[dreg[k].z - base], (unsigned long long)(long long)(tz * FP_SCALE));
        atomicAdd((unsigned long long*)&aggS[dreg[k].w - base], (unsigned long long)(long long)(tw * FP_SCALE));
    }
    __syncthreads();

    // --- score ---
    float si;
    {
        double sum = (double)aggS[tid] * FP_INV_SCALE + mS[tid];
        si = (float)(dinvS[tid] * sum + (double)bb);
        scoreS[tid] = si;
    }
    __syncthreads();   // all reads of aggS/mS/dinvS/degS complete -> safe to reuse

    // --- exact top-k via 1024-bin histogram on sortable keys ---
    uint32_t* keyS     = (uint32_t*)aggS;         // [1024] (bytes 0..4095 of aggS)
    float*    scaleR   = (float*)(keyS + NPG);    // bytes 4096..8191 of aggS (disjoint from keyS)
    uint32_t* hist     = (uint32_t*)dinvS;        // [1024]
    uint32_t* scanA    = hist + NPG;              // [1024]
    int*      mlist    = (int*)mS;                // [1024]
    int*      cursorS  = mlist + NPG;             // [1024]
    int*      rankNode = degS;                    // [1024]

    uint32_t sb = __float_as_uint(si);
    if (sb == 0x80000000u) sb = 0u;               // canonicalize -0 -> +0
    const uint32_t key = (sb & 0x80000000u) ? ~sb : (sb | 0x80000000u); // ascending order key
    keyS[tid]    = key;
    hist[tid]    = 0u;
    cursorS[tid] = 0;
    __syncthreads();

    const int bin = (int)(key >> 22);             // 1024 bins (sign+exp+1 mantissa bit)
    atomicAdd(&hist[bin], 1u);
    __syncthreads();

    // --- single-wave inclusive SUFFIX scan of hist -> scanA ---
    // Lane l owns bins [16l, 16l+16): serial within-lane suffix + 6-step
    // shfl_down butterfly across lane totals. Replaces 10-barrier Hillis-Steele.
    if (tid < 64) {
        const int lane = tid;
        uint32_t v[16];
        uint32_t tot = 0u;
        #pragma unroll
        for (int i = 0; i < 16; i++) { v[i] = hist[lane * 16 + i]; tot += v[i]; }
        uint32_t suf = tot;                        // will hold sum of tot[lane..63]
        #pragma unroll
        for (int off = 1; off < 64; off <<= 1) {
            uint32_t o = __shfl_down(suf, off, 64);
            if (lane + off < 64) suf += o;
        }
        uint32_t run = suf - tot;                  // total of lanes strictly above
        #pragma unroll
        for (int i = 15; i >= 0; i--) { run += v[i]; scanA[lane * 16 + i] = run; }
    }
    __syncthreads();

    const int myStart = (int)(scanA[bin] - hist[bin]);   // # nodes in strictly-higher bins
    {
        int slot = myStart + atomicAdd(&cursorS[bin], 1);
        mlist[slot] = tid;
    }
    __syncthreads();

    int rank = myStart;
    {
        const int h = (int)hist[bin];
        for (int m = 0; m < h; m++) {
            int j = mlist[myStart + m];
            uint32_t kj = keyS[j];
            rank += (kj > key) || (kj == key && j < tid);
        }
    }
    int pos = -1;
    if (rank < KSEL) {
        pos = g * KSEL + rank;
        rankNode[rank] = tid;
        scaleR[rank]   = tanhf(si);
        __builtin_nontemporal_store((float)g,            out_batch + pos);
        __builtin_nontemporal_store((float)(base + tid), out_perm  + pos);
    }
    lmap[tid] = pos;
    __syncthreads();

    // --- gather: x_ae = x[perm], x_out = x_ae * tanh(score) (32 lanes/row) ---
    {
        const int lane32 = tid & 31;
        const int rowgrp = tid >> 5;              // 0..31
        #pragma unroll
        for (int p = 0; p < 26; p++) {
            int r = p * 32 + rowgrp;
            if (r < KSEL) {
                int node = rankNode[r];
                float t  = scaleR[r];
                f32x4 v = *((const f32x4*)x + (size_t)(base + node) * 32 + lane32);
                f32x4 o = v * t;
                size_t orow = (size_t)(g * KSEL + r) * 32 + lane32;
                __builtin_nontemporal_store(v, (f32x4*)out_xae  + orow);
                __builtin_nontemporal_store(o, (f32x4*)out_xout + orow);
            }
        }
    }

    // --- edge outputs: mask + reindexed endpoints (lmap in LDS) ---
    // Last use of src: nontemporal loads (mostly L2/LLC hits from agg phase).
    #pragma unroll
    for (int k = 0; k < 8; k++) {
        int idx = tid + k * 1024;
        i32x4 s = __builtin_nontemporal_load(src4 + idx);
        i32x4 d = dreg[k];
        f32x4 e0, e1, m;
        int ms, md; bool kp;
        ms = lmap[s.x - base]; md = lmap[d.x - base]; kp = (ms >= 0) && (md >= 0);
        e0.x = kp ? (float)ms : -1.0f; e1.x = kp ? (float)md : -1.0f; m.x = kp ? 1.0f : 0.0f;
        ms = lmap[s.y - base]; md = lmap[d.y - base]; kp = (ms >= 0) && (md >= 0);
        e0.y = kp ? (float)ms : -1.0f; e1.y = kp ? (float)md : -1.0f; m.y = kp ? 1.0f : 0.0f;
        ms = lmap[s.z - base]; md = lmap[d.z - base]; kp = (ms >= 0) && (md >= 0);
        e0.z = kp ? (float)ms : -1.0f; e1.z = kp ? (float)md : -1.0f; m.z = kp ? 1.0f : 0.0f;
        ms = lmap[s.w - base]; md = lmap[d.w - base]; kp = (ms >= 0) && (md >= 0);
        e0.w = kp ? (float)ms : -1.0f; e1.w = kp ? (float)md : -1.0f; m.w = kp ? 1.0f : 0.0f;
        size_t o = (size_t)g * (EPG / 4) + idx;
        __builtin_nontemporal_store(e0, (f32x4*)out_ei0  + o);
        __builtin_nontemporal_store(e1, (f32x4*)out_ei1  + o);
        __builtin_nontemporal_store(m,  (f32x4*)out_mask + o);
    }
}

extern "C" void kernel_launch(void* const* d_in, const int* in_sizes, int n_in,
                              void* d_out, int out_size, void* d_ws, size_t ws_size,
                              hipStream_t stream) {
    const float* x  = (const float*)d_in[0];
    const int*   ei = (const int*)d_in[1];     // [2, E]: src then dst
    // d_in[2] = batch (unused; graphs are block-contiguous, recomputed)
    const float* W  = (const float*)d_in[3];
    const float* b  = (const float*)d_in[4];

    // output layout (all float32, concatenated in reference return order)
    float* out       = (float*)d_out;
    float* out_xout  = out;                          // BK*128
    float* out_ei0   = out + (size_t)BK * D_FEAT;    // E
    float* out_ei1   = out_ei0 + E_TOTAL;            // E
    float* out_mask  = out_ei1 + E_TOTAL;            // E
    float* out_batch = out_mask + E_TOTAL;           // BK
    float* out_perm  = out_batch + BK;               // BK
    float* out_xae   = out_perm + BK;                // BK*128

    sagpool_fused<<<NUM_G, 1024, 0, stream>>>(x, ei, W, b,
                                              out_xout, out_xae,
                                              out_ei0, out_ei1, out_mask,
                                              out_batch, out_perm);
}